// Round 12
// baseline (196.951 us; speedup 1.0000x reference)
//
#include <hip/hip_runtime.h>
#include <hip/hip_bf16.h>

// Round 12: attn load-balance fix. r5/r10/r11 all pinned at ~44us with
// OccupancyPercent 12% (should be 25% at 2 blocks/CU) -> static qt pairing
// fails (workgroup->CU assignment not controllable); wall = max-loaded CU.
// Fix: persistent attn kernel (512 workers = 2/CU) + atomic job queue of
// 1024 64-row q-tile jobs, heavy-first (LPT). Queue counter = __device__ int,
// reset by prep_k each launch (device-side reset, graph-capture-safe - r9).
// Body = r11's verified no-LDS/no-barrier chain. qkv/out/prep unchanged.

typedef __bf16 bf16_t;
typedef __bf16 bf16x4 __attribute__((ext_vector_type(4)));
typedef __bf16 bf16x8 __attribute__((ext_vector_type(8)));
typedef float f32x4 __attribute__((ext_vector_type(4)));

__device__ int g_job;

__device__ __forceinline__ void barrier_lgkm() {
    asm volatile("s_waitcnt lgkmcnt(0)\n\ts_barrier" ::: "memory");
}

__device__ __forceinline__ float exp_pwrite(f32x4 sc[4], bf16_t* Ps,
                                            int wave, int quad, int l16) {
    float part = 0.f;
    int rowbase = (wave * 16 + l16) * 64;
    int gran = (quad & 1) * 4;
    int chi = quad >> 1;
#pragma unroll
    for (int nt = 0; nt < 4; nt++) {
        f32x4 p;
#pragma unroll
        for (int rr = 0; rr < 4; rr++) {
            p[rr] = __builtin_amdgcn_exp2f(sc[nt][rr]);
            part += p[rr];
        }
        bf16x4 pb;
#pragma unroll
        for (int rr = 0; rr < 4; rr++) pb[rr] = (bf16_t)p[rr];
        int cc = (nt * 2 + chi) ^ (l16 & 7);
        *(bf16x4*)(Ps + rowbase + cc * 8 + gran) = pb;
    }
    part += __shfl_xor(part, 16);
    part += __shfl_xor(part, 32);
    return part;
}

// ---------------- prep: fused x cvt + 4x weight transpose + queue reset ------
__global__ __launch_bounds__(256) void prep_k(
    const float* __restrict__ x, const float* __restrict__ W0,
    const float* __restrict__ W1, const float* __restrict__ W2,
    const float* __restrict__ W3, bf16_t* __restrict__ xb,
    bf16_t* __restrict__ WTs) {
    __shared__ bf16_t T[64][65];
    int t = threadIdx.x;
    int blk = blockIdx.x;
    if (blk == 0 && t == 0) g_job = 0;
    if (blk < 4096) {
        int i = blk * 256 + t;
        float4 v = ((const float4*)x)[i];
        bf16x4 o;
        o[0] = (bf16_t)v.x; o[1] = (bf16_t)v.y;
        o[2] = (bf16_t)v.z; o[3] = (bf16_t)v.w;
        ((bf16x4*)xb)[i] = o;
        return;
    }
    int jj = blk - 4096;
    int k0 = (jj & 15) * 64, n0 = ((jj >> 4) & 15) * 64, z = jj >> 8;
    const float* W = (z == 0) ? W0 : (z == 1) ? W1 : (z == 2) ? W2 : W3;
    bf16_t* WT = WTs + (size_t)z * 1048576;
#pragma unroll
    for (int c = 0; c < 4; c++) {
        int idx = c * 256 + t;
        int row = idx >> 4, col4 = (idx & 15) * 4;
        float4 v = *(const float4*)(W + (k0 + row) * 1024 + n0 + col4);
        T[row][col4 + 0] = (bf16_t)v.x;
        T[row][col4 + 1] = (bf16_t)v.y;
        T[row][col4 + 2] = (bf16_t)v.z;
        T[row][col4 + 3] = (bf16_t)v.w;
    }
    __syncthreads();
#pragma unroll
    for (int c = 0; c < 4; c++) {
        int idx = c * 256 + t;
        int nrow = idx >> 4, kc4 = (idx & 15) * 4;
        bf16x4 o;
        o[0] = T[kc4 + 0][nrow];
        o[1] = T[kc4 + 1][nrow];
        o[2] = T[kc4 + 2][nrow];
        o[3] = T[kc4 + 3][nrow];
        *(bf16x4*)(WT + (n0 + nrow) * 1024 + k0 + kc4) = o;
    }
}

// ---------------- qkv GEMM (r6 body, unchanged) ----------------
__global__ __launch_bounds__(256) void qkv_k(
    const bf16_t* __restrict__ xb, const bf16_t* __restrict__ WTs,
    bf16_t* __restrict__ Qb, bf16_t* __restrict__ Kb, bf16_t* __restrict__ Vb) {
    const int KD = 1024;
    __shared__ __align__(16) bf16_t As[2][4096];
    __shared__ __align__(16) bf16_t Bs[2][4096];
    int tid = threadIdx.x;
    int wave = tid >> 6, lane = tid & 63;
    int quad = lane >> 4, l16 = lane & 15;
    int wm = wave >> 1, wn = wave & 1;
    int z = blockIdx.z;
    const bf16_t* BT = WTs + (size_t)z * 1048576;
    int m0 = blockIdx.x * 128;
    int n0 = blockIdx.y * 128;

    int r = tid >> 2;
    int c8 = (((tid & 3) ^ ((tid >> 3) & 3))) * 8;
    const bf16_t* gA0 = xb + (size_t)(m0 + r) * KD + c8;
    const bf16_t* gA1 = xb + (size_t)(m0 + 64 + r) * KD + c8;
    const bf16_t* gB0 = BT + (size_t)(n0 + r) * KD + c8;
    const bf16_t* gB1 = BT + (size_t)(n0 + 64 + r) * KD + c8;

    f32x4 acc[4][4];
#pragma unroll
    for (int i = 0; i < 4; i++)
#pragma unroll
        for (int j = 0; j < 4; j++) acc[i][j] = (f32x4){0.f, 0.f, 0.f, 0.f};

    int4 sa0 = *(const int4*)gA0, sa1 = *(const int4*)gA1;
    int4 sb0 = *(const int4*)gB0, sb1 = *(const int4*)gB1;
    *(int4*)(As[0] + tid * 8) = sa0;
    *(int4*)(As[0] + 2048 + tid * 8) = sa1;
    *(int4*)(Bs[0] + tid * 8) = sb0;
    *(int4*)(Bs[0] + 2048 + tid * 8) = sb1;
    sa0 = *(const int4*)(gA0 + 32); sa1 = *(const int4*)(gA1 + 32);
    sb0 = *(const int4*)(gB0 + 32); sb1 = *(const int4*)(gB1 + 32);

    int csw = (quad ^ ((l16 >> 1) & 3)) * 8;
#pragma unroll 1
    for (int kk = 0; kk < 32; kk += 2) {
        barrier_lgkm();
        bf16x8 af[4], bfr[4];
#pragma unroll
        for (int mt = 0; mt < 4; mt++)
            af[mt] = *(const bf16x8*)(As[0] + (wm * 64 + mt * 16 + l16) * 32 + csw);
#pragma unroll
        for (int nt = 0; nt < 4; nt++)
            bfr[nt] = *(const bf16x8*)(Bs[0] + (wn * 64 + nt * 16 + l16) * 32 + csw);
        *(int4*)(As[1] + tid * 8) = sa0;
        *(int4*)(As[1] + 2048 + tid * 8) = sa1;
        *(int4*)(Bs[1] + tid * 8) = sb0;
        *(int4*)(Bs[1] + 2048 + tid * 8) = sb1;
        if (kk + 2 < 32) {
            int k0 = (kk + 2) * 32;
            sa0 = *(const int4*)(gA0 + k0); sa1 = *(const int4*)(gA1 + k0);
            sb0 = *(const int4*)(gB0 + k0); sb1 = *(const int4*)(gB1 + k0);
        }
        if (z == 2) {
#pragma unroll
            for (int mt = 0; mt < 4; mt++)
#pragma unroll
                for (int nt = 0; nt < 4; nt++)
                    acc[mt][nt] = __builtin_amdgcn_mfma_f32_16x16x32_bf16(
                        bfr[nt], af[mt], acc[mt][nt], 0, 0, 0);
        } else {
#pragma unroll
            for (int mt = 0; mt < 4; mt++)
#pragma unroll
                for (int nt = 0; nt < 4; nt++)
                    acc[mt][nt] = __builtin_amdgcn_mfma_f32_16x16x32_bf16(
                        af[mt], bfr[nt], acc[mt][nt], 0, 0, 0);
        }
        barrier_lgkm();
#pragma unroll
        for (int mt = 0; mt < 4; mt++)
            af[mt] = *(const bf16x8*)(As[1] + (wm * 64 + mt * 16 + l16) * 32 + csw);
#pragma unroll
        for (int nt = 0; nt < 4; nt++)
            bfr[nt] = *(const bf16x8*)(Bs[1] + (wn * 64 + nt * 16 + l16) * 32 + csw);
        if (kk + 2 < 32) {
            *(int4*)(As[0] + tid * 8) = sa0;
            *(int4*)(As[0] + 2048 + tid * 8) = sa1;
            *(int4*)(Bs[0] + tid * 8) = sb0;
            *(int4*)(Bs[0] + 2048 + tid * 8) = sb1;
            if (kk + 3 < 32) {
                int k0 = (kk + 3) * 32;
                sa0 = *(const int4*)(gA0 + k0); sa1 = *(const int4*)(gA1 + k0);
                sb0 = *(const int4*)(gB0 + k0); sb1 = *(const int4*)(gB1 + k0);
            }
        }
        if (z == 2) {
#pragma unroll
            for (int mt = 0; mt < 4; mt++)
#pragma unroll
                for (int nt = 0; nt < 4; nt++)
                    acc[mt][nt] = __builtin_amdgcn_mfma_f32_16x16x32_bf16(
                        bfr[nt], af[mt], acc[mt][nt], 0, 0, 0);
        } else {
#pragma unroll
            for (int mt = 0; mt < 4; mt++)
#pragma unroll
                for (int nt = 0; nt < 4; nt++)
                    acc[mt][nt] = __builtin_amdgcn_mfma_f32_16x16x32_bf16(
                        af[mt], bfr[nt], acc[mt][nt], 0, 0, 0);
        }
    }

    if (z == 0) {
#pragma unroll
        for (int mt = 0; mt < 4; mt++) {
            int mg_base = m0 + wm * 64 + mt * 16 + quad * 4;
#pragma unroll
            for (int nt = 0; nt < 4; nt++) {
                int ng = n0 + wn * 64 + nt * 16 + l16;
                int h = ng >> 6, d = ng & 63;
#pragma unroll
                for (int rr = 0; rr < 4; rr++) {
                    int mg = mg_base + rr;
                    int b = mg >> 11, s = mg & 2047;
                    Qb[(((size_t)(b * 16 + h) * 2048) + s) * 64 + d] =
                        (bf16_t)acc[mt][nt][rr];
                }
            }
        }
    } else if (z == 1) {
#pragma unroll
        for (int mt = 0; mt < 4; mt++) {
            int mg_base = m0 + wm * 64 + mt * 16 + quad * 4;
#pragma unroll
            for (int nt = 0; nt < 4; nt++) {
                int ng = n0 + wn * 64 + nt * 16 + l16;
                int h = ng >> 6, dd = ng & 63;
#pragma unroll
                for (int rr = 0; rr < 4; rr++) {
                    int mg = mg_base + rr;
                    int b = mg >> 11, sl = mg & 2047;
                    int kt = sl >> 6, row = sl & 63;
                    int cc = (dd >> 3) ^ (row & 7);
                    Kb[(size_t)(b * 16 + h) * 131072 + kt * 4096 + row * 64 +
                       cc * 8 + (dd & 7)] = (bf16_t)acc[mt][nt][rr];
                }
            }
        }
    } else {
#pragma unroll
        for (int mt = 0; mt < 4; mt++) {
            int sg = m0 + wm * 64 + mt * 16 + l16;
            int b = sg >> 11, sl = sg & 2047;
            int kt = sl >> 6, srow = sl & 63;
#pragma unroll
            for (int nt = 0; nt < 4; nt++) {
                int dg_base = n0 + wn * 64 + nt * 16 + quad * 4;
#pragma unroll
                for (int rr = 0; rr < 4; rr++) {
                    int dg = dg_base + rr;
                    int h = dg >> 6, dd = dg & 63;
                    int cc = (srow >> 3) ^ (dd & 7);
                    Vb[(size_t)(b * 16 + h) * 131072 + kt * 4096 + dd * 64 +
                       cc * 8 + (srow & 7)] = (bf16_t)acc[mt][nt][rr];
                }
            }
        }
    }
}

// ---------------- attention: persistent queue, 64-row jobs, no-LDS K/V ------
// 512 workers (2/CU); 1024 jobs heavy-first: qt = 31-(j>>5), bh = j&31.
__global__ __launch_bounds__(256) void attn_k(
    const bf16_t* __restrict__ Qb, const bf16_t* __restrict__ Kb,
    const bf16_t* __restrict__ Vb, bf16_t* __restrict__ ctxb) {
    const int S = 2048;
    __shared__ __align__(16) bf16_t Ps[4096];
    __shared__ int s_job;
    int tid = threadIdx.x, wave = tid >> 6, lane = tid & 63;
    int quad = lane >> 4, l16 = lane & 15;
    const float qs = 0.125f * 1.44269504f;

    // per-lane fragment offsets within a 64x64 tile (match qkv's swizzle)
    int koff[4][2];
#pragma unroll
    for (int nt = 0; nt < 4; nt++)
#pragma unroll
        for (int ks = 0; ks < 2; ks++)
            koff[nt][ks] = (nt * 16 + l16) * 64 + ((ks * 4 + quad) ^ (l16 & 7)) * 8;

#pragma unroll 1
    while (true) {
        __syncthreads();
        if (tid == 0) s_job = atomicAdd(&g_job, 1);
        __syncthreads();
        int j = s_job;
        if (j >= 1024) break;
        int qt = 31 - (j >> 5);
        int bh = j & 31;
        int h = bh & 15, b = bh >> 4;
        int q0 = qt * 64;

        const bf16_t* Qbh = Qb + (size_t)bh * S * 64;
        const bf16_t* Kbh = Kb + (size_t)bh * 131072;
        const bf16_t* Vbh = Vb + (size_t)bh * 131072;

        bf16x8 aQ[2];
        {
            const bf16_t* rq = Qbh + (size_t)(q0 + wave * 16 + l16) * 64;
#pragma unroll
            for (int ks = 0; ks < 2; ks++) {
                bf16x8 t = *(const bf16x8*)(rq + ks * 32 + quad * 8);
#pragma unroll
                for (int jj = 0; jj < 8; jj++) t[jj] = (bf16_t)((float)t[jj] * qs);
                aQ[ks] = t;
            }
        }

        float L = 0.f;
        f32x4 O[4];
#pragma unroll
        for (int i = 0; i < 4; i++) O[i] = (f32x4){0.f, 0.f, 0.f, 0.f};

#pragma unroll 1
        for (int kt = 0; kt <= qt; kt++) {
            const bf16_t* kbase = Kbh + kt * 4096;
            const bf16_t* vbase = Vbh + kt * 4096;
            bf16x8 kf[4][2], vf[4][2];
#pragma unroll
            for (int nt = 0; nt < 4; nt++)
#pragma unroll
                for (int ks = 0; ks < 2; ks++) {
                    kf[nt][ks] = *(const bf16x8*)(kbase + koff[nt][ks]);
                    vf[nt][ks] = *(const bf16x8*)(vbase + koff[nt][ks]);
                }

            f32x4 sc[4];
#pragma unroll
            for (int nt = 0; nt < 4; nt++) {
                f32x4 ss = (f32x4){0.f, 0.f, 0.f, 0.f};
                ss = __builtin_amdgcn_mfma_f32_16x16x32_bf16(kf[nt][0], aQ[0], ss, 0, 0, 0);
                ss = __builtin_amdgcn_mfma_f32_16x16x32_bf16(kf[nt][1], aQ[1], ss, 0, 0, 0);
                sc[nt] = ss;
            }
            if (kt == qt) {  // causal mask on diagonal tile
                int qg = q0 + wave * 16 + l16;
#pragma unroll
                for (int nt = 0; nt < 4; nt++)
#pragma unroll
                    for (int rr = 0; rr < 4; rr++)
                        if (kt * 64 + nt * 16 + quad * 4 + rr > qg) sc[nt][rr] = -1e30f;
            }
            L += exp_pwrite(sc, Ps, wave, quad, l16);

            // O += P @ V (Ps slab wave-private; wave-local LDS in-order)
#pragma unroll
            for (int ks = 0; ks < 2; ks++) {
                int csw = ((ks * 4 + quad) ^ (l16 & 7)) * 8;
                bf16x8 aP = *(const bf16x8*)(Ps + (wave * 16 + l16) * 64 + csw);
#pragma unroll
                for (int nt = 0; nt < 4; nt++)
                    O[nt] = __builtin_amdgcn_mfma_f32_16x16x32_bf16(aP, vf[nt][ks],
                                                                    O[nt], 0, 0, 0);
            }
        }

        float il[4];
#pragma unroll
        for (int rr = 0; rr < 4; rr++) il[rr] = 1.f / __shfl(L, quad * 4 + rr);
#pragma unroll
        for (int nt = 0; nt < 4; nt++) {
#pragma unroll
            for (int rr = 0; rr < 4; rr++) {
                int qoff = q0 + wave * 16 + quad * 4 + rr;
                int col = h * 64 + nt * 16 + l16;
                ctxb[(size_t)(b * 2048 + qoff) * 1024 + col] =
                    (bf16_t)(O[nt][rr] * il[rr]);
            }
        }
    }
}

// ---------------- out projection (r6 body, unchanged) ----------------
__global__ __launch_bounds__(256) void out_k(
    const bf16_t* __restrict__ ctxb, const bf16_t* __restrict__ WoT,
    const float* __restrict__ bo, float* __restrict__ out) {
    const int KD = 1024;
    __shared__ __align__(16) bf16_t As[2][2048];
    __shared__ __align__(16) bf16_t Bs[2][4096];
    int tid = threadIdx.x;
    int wave = tid >> 6, lane = tid & 63;
    int quad = lane >> 4, l16 = lane & 15;
    int wm = wave >> 1, wn = wave & 1;
    int m0 = blockIdx.x * 64;
    int n0 = blockIdx.y * 128;

    int r = tid >> 2;
    int c8 = (((tid & 3) ^ ((tid >> 3) & 3))) * 8;
    const bf16_t* gA  = ctxb + (size_t)(m0 + r) * KD + c8;
    const bf16_t* gB0 = WoT + (size_t)(n0 + r) * KD + c8;
    const bf16_t* gB1 = WoT + (size_t)(n0 + 64 + r) * KD + c8;

    f32x4 acc[2][4];
#pragma unroll
    for (int i = 0; i < 2; i++)
#pragma unroll
        for (int j = 0; j < 4; j++) acc[i][j] = (f32x4){0.f, 0.f, 0.f, 0.f};

    int4 sa = *(const int4*)gA;
    int4 sb0 = *(const int4*)gB0, sb1 = *(const int4*)gB1;
    *(int4*)(As[0] + tid * 8) = sa;
    *(int4*)(Bs[0] + tid * 8) = sb0;
    *(int4*)(Bs[0] + 2048 + tid * 8) = sb1;
    sa = *(const int4*)(gA + 32);
    sb0 = *(const int4*)(gB0 + 32); sb1 = *(const int4*)(gB1 + 32);

    int csw = (quad ^ ((l16 >> 1) & 3)) * 8;
#pragma unroll 1
    for (int kk = 0; kk < 32; kk += 2) {
        barrier_lgkm();
        bf16x8 af[2], bfr[4];
#pragma unroll
        for (int mt = 0; mt < 2; mt++)
            af[mt] = *(const bf16x8*)(As[0] + (wm * 32 + mt * 16 + l16) * 32 + csw);
#pragma unroll
        for (int nt = 0; nt < 4; nt++)
            bfr[nt] = *(const bf16x8*)(Bs[0] + (wn * 64 + nt * 16 + l16) * 32 + csw);
        *(int4*)(As[1] + tid * 8) = sa;
        *(int4*)(Bs[1] + tid * 8) = sb0;
        *(int4*)(Bs[1] + 2048 + tid * 8) = sb1;
        if (kk + 2 < 32) {
            int k0 = (kk + 2) * 32;
            sa = *(const int4*)(gA + k0);
            sb0 = *(const int4*)(gB0 + k0); sb1 = *(const int4*)(gB1 + k0);
        }
#pragma unroll
        for (int mt = 0; mt < 2; mt++)
#pragma unroll
            for (int nt = 0; nt < 4; nt++)
                acc[mt][nt] = __builtin_amdgcn_mfma_f32_16x16x32_bf16(
                    af[mt], bfr[nt], acc[mt][nt], 0, 0, 0);
        barrier_lgkm();
#pragma unroll
        for (int mt = 0; mt < 2; mt++)
            af[mt] = *(const bf16x8*)(As[1] + (wm * 32 + mt * 16 + l16) * 32 + csw);
#pragma unroll
        for (int nt = 0; nt < 4; nt++)
            bfr[nt] = *(const bf16x8*)(Bs[1] + (wn * 64 + nt * 16 + l16) * 32 + csw);
        if (kk + 2 < 32) {
            *(int4*)(As[0] + tid * 8) = sa;
            *(int4*)(Bs[0] + tid * 8) = sb0;
            *(int4*)(Bs[0] + 2048 + tid * 8) = sb1;
            if (kk + 3 < 32) {
                int k0 = (kk + 3) * 32;
                sa = *(const int4*)(gA + k0);
                sb0 = *(const int4*)(gB0 + k0); sb1 = *(const int4*)(gB1 + k0);
            }
        }
#pragma unroll
        for (int mt = 0; mt < 2; mt++)
#pragma unroll
            for (int nt = 0; nt < 4; nt++)
                acc[mt][nt] = __builtin_amdgcn_mfma_f32_16x16x32_bf16(
                    af[mt], bfr[nt], acc[mt][nt], 0, 0, 0);
    }

#pragma unroll
    for (int mt = 0; mt < 2; mt++) {
        int mg_base = m0 + wm * 32 + mt * 16 + quad * 4;
#pragma unroll
        for (int nt = 0; nt < 4; nt++) {
            int ng = n0 + wn * 64 + nt * 16 + l16;
            float bv = bo[ng];
#pragma unroll
            for (int rr = 0; rr < 4; rr++) {
                int mg = mg_base + rr;
                out[(size_t)mg * 1024 + ng] = acc[mt][nt][rr] + bv;
            }
        }
    }
}

extern "C" void kernel_launch(void* const* d_in, const int* in_sizes, int n_in,
                              void* d_out, int out_size, void* d_ws, size_t ws_size,
                              hipStream_t stream) {
    const float* x  = (const float*)d_in[0];
    const float* Wq = (const float*)d_in[1];
    const float* Wk = (const float*)d_in[2];
    const float* Wv = (const float*)d_in[3];
    const float* Wo = (const float*)d_in[4];
    const float* bo = (const float*)d_in[5];
    float* out = (float*)d_out;
    char* ws = (char*)d_ws;

    bf16_t* xb   = (bf16_t*)ws;                  // 8 MB
    bf16_t* WTs  = (bf16_t*)(ws + (8u << 20));   // 4x2 MB
    bf16_t* Qb   = (bf16_t*)(ws + (16u << 20));  // 8 MB natural
    bf16_t* Kb   = (bf16_t*)(ws + (24u << 20));  // 8 MB tiled-swizzled
    bf16_t* Vb   = (bf16_t*)(ws + (32u << 20));  // 8 MB tiled-swizzled V^T
    bf16_t* ctxb = (bf16_t*)(ws + (40u << 20));  // 8 MB

    prep_k<<<5120, 256, 0, stream>>>(x, Wq, Wk, Wv, Wo, xb, WTs);
    qkv_k<<<dim3(32, 8, 3), 256, 0, stream>>>(xb, WTs, Qb, Kb, Vb);
    attn_k<<<512, 256, 0, stream>>>(Qb, Kb, Vb, ctxb);
    out_k<<<dim3(64, 8), 256, 0, stream>>>(ctxb, WTs + 3145728, bo, out);
}

// Round 13
// 191.232 us; speedup vs baseline: 1.0299x; 1.0299x over previous
//
#include <hip/hip_runtime.h>
#include <hip/hip_bf16.h>

// Round 13: r11 attn (best known: XCD-pinned, no-LDS K/V, dual subtile)
// + register ping-pong software pipeline over K-tiles: tile kt+1's kf/vf
// global loads are issued before tile kt's compute chain (S->exp->Ps->PV),
// hiding L1/L2 load latency inside the wave. No queue (r12 destroyed L2
// locality: FETCH 12->90GB, 44->66us). prep/qkv/out unchanged from r11.

typedef __bf16 bf16_t;
typedef __bf16 bf16x4 __attribute__((ext_vector_type(4)));
typedef __bf16 bf16x8 __attribute__((ext_vector_type(8)));
typedef float f32x4 __attribute__((ext_vector_type(4)));

__device__ __forceinline__ void barrier_lgkm() {
    asm volatile("s_waitcnt lgkmcnt(0)\n\ts_barrier" ::: "memory");
}

__device__ __forceinline__ float exp_pwrite(f32x4 sc[4], bf16_t* Ps,
                                            int wave, int quad, int l16) {
    float part = 0.f;
    int rowbase = (wave * 16 + l16) * 64;
    int gran = (quad & 1) * 4;
    int chi = quad >> 1;
#pragma unroll
    for (int nt = 0; nt < 4; nt++) {
        f32x4 p;
#pragma unroll
        for (int rr = 0; rr < 4; rr++) {
            p[rr] = __builtin_amdgcn_exp2f(sc[nt][rr]);
            part += p[rr];
        }
        bf16x4 pb;
#pragma unroll
        for (int rr = 0; rr < 4; rr++) pb[rr] = (bf16_t)p[rr];
        int cc = (nt * 2 + chi) ^ (l16 & 7);
        *(bf16x4*)(Ps + rowbase + cc * 8 + gran) = pb;
    }
    part += __shfl_xor(part, 16);
    part += __shfl_xor(part, 32);
    return part;
}

// ---------------- prep: fused x cvt + 4x weight transpose ----------------
__global__ __launch_bounds__(256) void prep_k(
    const float* __restrict__ x, const float* __restrict__ W0,
    const float* __restrict__ W1, const float* __restrict__ W2,
    const float* __restrict__ W3, bf16_t* __restrict__ xb,
    bf16_t* __restrict__ WTs) {
    __shared__ bf16_t T[64][65];
    int t = threadIdx.x;
    int blk = blockIdx.x;
    if (blk < 4096) {
        int i = blk * 256 + t;
        float4 v = ((const float4*)x)[i];
        bf16x4 o;
        o[0] = (bf16_t)v.x; o[1] = (bf16_t)v.y;
        o[2] = (bf16_t)v.z; o[3] = (bf16_t)v.w;
        ((bf16x4*)xb)[i] = o;
        return;
    }
    int jj = blk - 4096;
    int k0 = (jj & 15) * 64, n0 = ((jj >> 4) & 15) * 64, z = jj >> 8;
    const float* W = (z == 0) ? W0 : (z == 1) ? W1 : (z == 2) ? W2 : W3;
    bf16_t* WT = WTs + (size_t)z * 1048576;
#pragma unroll
    for (int c = 0; c < 4; c++) {
        int idx = c * 256 + t;
        int row = idx >> 4, col4 = (idx & 15) * 4;
        float4 v = *(const float4*)(W + (k0 + row) * 1024 + n0 + col4);
        T[row][col4 + 0] = (bf16_t)v.x;
        T[row][col4 + 1] = (bf16_t)v.y;
        T[row][col4 + 2] = (bf16_t)v.z;
        T[row][col4 + 3] = (bf16_t)v.w;
    }
    __syncthreads();
#pragma unroll
    for (int c = 0; c < 4; c++) {
        int idx = c * 256 + t;
        int nrow = idx >> 4, kc4 = (idx & 15) * 4;
        bf16x4 o;
        o[0] = T[kc4 + 0][nrow];
        o[1] = T[kc4 + 1][nrow];
        o[2] = T[kc4 + 2][nrow];
        o[3] = T[kc4 + 3][nrow];
        *(bf16x4*)(WT + (n0 + nrow) * 1024 + k0 + kc4) = o;
    }
}

// ---------------- qkv GEMM (r6 body, unchanged) ----------------
__global__ __launch_bounds__(256) void qkv_k(
    const bf16_t* __restrict__ xb, const bf16_t* __restrict__ WTs,
    bf16_t* __restrict__ Qb, bf16_t* __restrict__ Kb, bf16_t* __restrict__ Vb) {
    const int KD = 1024;
    __shared__ __align__(16) bf16_t As[2][4096];
    __shared__ __align__(16) bf16_t Bs[2][4096];
    int tid = threadIdx.x;
    int wave = tid >> 6, lane = tid & 63;
    int quad = lane >> 4, l16 = lane & 15;
    int wm = wave >> 1, wn = wave & 1;
    int z = blockIdx.z;
    const bf16_t* BT = WTs + (size_t)z * 1048576;
    int m0 = blockIdx.x * 128;
    int n0 = blockIdx.y * 128;

    int r = tid >> 2;
    int c8 = (((tid & 3) ^ ((tid >> 3) & 3))) * 8;
    const bf16_t* gA0 = xb + (size_t)(m0 + r) * KD + c8;
    const bf16_t* gA1 = xb + (size_t)(m0 + 64 + r) * KD + c8;
    const bf16_t* gB0 = BT + (size_t)(n0 + r) * KD + c8;
    const bf16_t* gB1 = BT + (size_t)(n0 + 64 + r) * KD + c8;

    f32x4 acc[4][4];
#pragma unroll
    for (int i = 0; i < 4; i++)
#pragma unroll
        for (int j = 0; j < 4; j++) acc[i][j] = (f32x4){0.f, 0.f, 0.f, 0.f};

    int4 sa0 = *(const int4*)gA0, sa1 = *(const int4*)gA1;
    int4 sb0 = *(const int4*)gB0, sb1 = *(const int4*)gB1;
    *(int4*)(As[0] + tid * 8) = sa0;
    *(int4*)(As[0] + 2048 + tid * 8) = sa1;
    *(int4*)(Bs[0] + tid * 8) = sb0;
    *(int4*)(Bs[0] + 2048 + tid * 8) = sb1;
    sa0 = *(const int4*)(gA0 + 32); sa1 = *(const int4*)(gA1 + 32);
    sb0 = *(const int4*)(gB0 + 32); sb1 = *(const int4*)(gB1 + 32);

    int csw = (quad ^ ((l16 >> 1) & 3)) * 8;
#pragma unroll 1
    for (int kk = 0; kk < 32; kk += 2) {
        barrier_lgkm();
        bf16x8 af[4], bfr[4];
#pragma unroll
        for (int mt = 0; mt < 4; mt++)
            af[mt] = *(const bf16x8*)(As[0] + (wm * 64 + mt * 16 + l16) * 32 + csw);
#pragma unroll
        for (int nt = 0; nt < 4; nt++)
            bfr[nt] = *(const bf16x8*)(Bs[0] + (wn * 64 + nt * 16 + l16) * 32 + csw);
        *(int4*)(As[1] + tid * 8) = sa0;
        *(int4*)(As[1] + 2048 + tid * 8) = sa1;
        *(int4*)(Bs[1] + tid * 8) = sb0;
        *(int4*)(Bs[1] + 2048 + tid * 8) = sb1;
        if (kk + 2 < 32) {
            int k0 = (kk + 2) * 32;
            sa0 = *(const int4*)(gA0 + k0); sa1 = *(const int4*)(gA1 + k0);
            sb0 = *(const int4*)(gB0 + k0); sb1 = *(const int4*)(gB1 + k0);
        }
        if (z == 2) {
#pragma unroll
            for (int mt = 0; mt < 4; mt++)
#pragma unroll
                for (int nt = 0; nt < 4; nt++)
                    acc[mt][nt] = __builtin_amdgcn_mfma_f32_16x16x32_bf16(
                        bfr[nt], af[mt], acc[mt][nt], 0, 0, 0);
        } else {
#pragma unroll
            for (int mt = 0; mt < 4; mt++)
#pragma unroll
                for (int nt = 0; nt < 4; nt++)
                    acc[mt][nt] = __builtin_amdgcn_mfma_f32_16x16x32_bf16(
                        af[mt], bfr[nt], acc[mt][nt], 0, 0, 0);
        }
        barrier_lgkm();
#pragma unroll
        for (int mt = 0; mt < 4; mt++)
            af[mt] = *(const bf16x8*)(As[1] + (wm * 64 + mt * 16 + l16) * 32 + csw);
#pragma unroll
        for (int nt = 0; nt < 4; nt++)
            bfr[nt] = *(const bf16x8*)(Bs[1] + (wn * 64 + nt * 16 + l16) * 32 + csw);
        if (kk + 2 < 32) {
            *(int4*)(As[0] + tid * 8) = sa0;
            *(int4*)(As[0] + 2048 + tid * 8) = sa1;
            *(int4*)(Bs[0] + tid * 8) = sb0;
            *(int4*)(Bs[0] + 2048 + tid * 8) = sb1;
            if (kk + 3 < 32) {
                int k0 = (kk + 3) * 32;
                sa0 = *(const int4*)(gA0 + k0); sa1 = *(const int4*)(gA1 + k0);
                sb0 = *(const int4*)(gB0 + k0); sb1 = *(const int4*)(gB1 + k0);
            }
        }
        if (z == 2) {
#pragma unroll
            for (int mt = 0; mt < 4; mt++)
#pragma unroll
                for (int nt = 0; nt < 4; nt++)
                    acc[mt][nt] = __builtin_amdgcn_mfma_f32_16x16x32_bf16(
                        bfr[nt], af[mt], acc[mt][nt], 0, 0, 0);
        } else {
#pragma unroll
            for (int mt = 0; mt < 4; mt++)
#pragma unroll
                for (int nt = 0; nt < 4; nt++)
                    acc[mt][nt] = __builtin_amdgcn_mfma_f32_16x16x32_bf16(
                        af[mt], bfr[nt], acc[mt][nt], 0, 0, 0);
        }
    }

    if (z == 0) {
#pragma unroll
        for (int mt = 0; mt < 4; mt++) {
            int mg_base = m0 + wm * 64 + mt * 16 + quad * 4;
#pragma unroll
            for (int nt = 0; nt < 4; nt++) {
                int ng = n0 + wn * 64 + nt * 16 + l16;
                int h = ng >> 6, d = ng & 63;
#pragma unroll
                for (int rr = 0; rr < 4; rr++) {
                    int mg = mg_base + rr;
                    int b = mg >> 11, s = mg & 2047;
                    Qb[(((size_t)(b * 16 + h) * 2048) + s) * 64 + d] =
                        (bf16_t)acc[mt][nt][rr];
                }
            }
        }
    } else if (z == 1) {
#pragma unroll
        for (int mt = 0; mt < 4; mt++) {
            int mg_base = m0 + wm * 64 + mt * 16 + quad * 4;
#pragma unroll
            for (int nt = 0; nt < 4; nt++) {
                int ng = n0 + wn * 64 + nt * 16 + l16;
                int h = ng >> 6, dd = ng & 63;
#pragma unroll
                for (int rr = 0; rr < 4; rr++) {
                    int mg = mg_base + rr;
                    int b = mg >> 11, sl = mg & 2047;
                    int kt = sl >> 6, row = sl & 63;
                    int cc = (dd >> 3) ^ (row & 7);
                    Kb[(size_t)(b * 16 + h) * 131072 + kt * 4096 + row * 64 +
                       cc * 8 + (dd & 7)] = (bf16_t)acc[mt][nt][rr];
                }
            }
        }
    } else {
#pragma unroll
        for (int mt = 0; mt < 4; mt++) {
            int sg = m0 + wm * 64 + mt * 16 + l16;
            int b = sg >> 11, sl = sg & 2047;
            int kt = sl >> 6, srow = sl & 63;
#pragma unroll
            for (int nt = 0; nt < 4; nt++) {
                int dg_base = n0 + wn * 64 + nt * 16 + quad * 4;
#pragma unroll
                for (int rr = 0; rr < 4; rr++) {
                    int dg = dg_base + rr;
                    int h = dg >> 6, dd = dg & 63;
                    int cc = (srow >> 3) ^ (dd & 7);
                    Vb[(size_t)(b * 16 + h) * 131072 + kt * 4096 + dd * 64 +
                       cc * 8 + (srow & 7)] = (bf16_t)acc[mt][nt][rr];
                }
            }
        }
    }
}

// ---------------- attention helpers ----------------
__device__ __forceinline__ void attn_load(
    bf16x8 kf[4][2], bf16x8 vf[4][2], const bf16_t* Kbh, const bf16_t* Vbh,
    int kt, const int koff[4][2]) {
    const bf16_t* kbase = Kbh + kt * 4096;
    const bf16_t* vbase = Vbh + kt * 4096;
#pragma unroll
    for (int nt = 0; nt < 4; nt++)
#pragma unroll
        for (int ks = 0; ks < 2; ks++) {
            kf[nt][ks] = *(const bf16x8*)(kbase + koff[nt][ks]);
            vf[nt][ks] = *(const bf16x8*)(vbase + koff[nt][ks]);
        }
}

__device__ __forceinline__ void attn_proc(
    int kt, int tmax, int q0, const bf16x8 kf[4][2], const bf16x8 vf[4][2],
    const bf16x8 aQ[2][2], float L[2], f32x4 O[2][4],
    bf16_t* Ps0, bf16_t* Ps1, int wave, int quad, int l16) {
    bool do_lo = (kt < tmax - 1);
    if (do_lo) {
        f32x4 sc[4];
#pragma unroll
        for (int nt = 0; nt < 4; nt++) {
            f32x4 ss = (f32x4){0.f, 0.f, 0.f, 0.f};
            ss = __builtin_amdgcn_mfma_f32_16x16x32_bf16(kf[nt][0], aQ[0][0], ss, 0, 0, 0);
            ss = __builtin_amdgcn_mfma_f32_16x16x32_bf16(kf[nt][1], aQ[0][1], ss, 0, 0, 0);
            sc[nt] = ss;
        }
        if (kt == tmax - 2) {
            int qg = q0 + wave * 16 + l16;
#pragma unroll
            for (int nt = 0; nt < 4; nt++)
#pragma unroll
                for (int rr = 0; rr < 4; rr++)
                    if (kt * 64 + nt * 16 + quad * 4 + rr > qg) sc[nt][rr] = -1e30f;
        }
        L[0] += exp_pwrite(sc, Ps0, wave, quad, l16);
    }
    {
        f32x4 sc[4];
#pragma unroll
        for (int nt = 0; nt < 4; nt++) {
            f32x4 ss = (f32x4){0.f, 0.f, 0.f, 0.f};
            ss = __builtin_amdgcn_mfma_f32_16x16x32_bf16(kf[nt][0], aQ[1][0], ss, 0, 0, 0);
            ss = __builtin_amdgcn_mfma_f32_16x16x32_bf16(kf[nt][1], aQ[1][1], ss, 0, 0, 0);
            sc[nt] = ss;
        }
        if (kt == tmax - 1) {
            int qg = q0 + 64 + wave * 16 + l16;
#pragma unroll
            for (int nt = 0; nt < 4; nt++)
#pragma unroll
                for (int rr = 0; rr < 4; rr++)
                    if (kt * 64 + nt * 16 + quad * 4 + rr > qg) sc[nt][rr] = -1e30f;
        }
        L[1] += exp_pwrite(sc, Ps1, wave, quad, l16);
    }
#pragma unroll
    for (int ks = 0; ks < 2; ks++) {
        int csw = ((ks * 4 + quad) ^ (l16 & 7)) * 8;
        bf16x8 aPhi = *(const bf16x8*)(Ps1 + (wave * 16 + l16) * 64 + csw);
        bf16x8 aPlo;
        if (do_lo) aPlo = *(const bf16x8*)(Ps0 + (wave * 16 + l16) * 64 + csw);
#pragma unroll
        for (int nt = 0; nt < 4; nt++) {
            O[1][nt] = __builtin_amdgcn_mfma_f32_16x16x32_bf16(aPhi, vf[nt][ks],
                                                               O[1][nt], 0, 0, 0);
            if (do_lo)
                O[0][nt] = __builtin_amdgcn_mfma_f32_16x16x32_bf16(aPlo, vf[nt][ks],
                                                                   O[0][nt], 0, 0, 0);
        }
    }
}

// ---------------- attention: no-LDS K/V, ping-pong prefetch ----------------
// grid 512. f&7 = XCD slot; per XCD: 4 bh x 16 qtj (128-row tiles).
__global__ __launch_bounds__(256) void attn_k(
    const bf16_t* __restrict__ Qb, const bf16_t* __restrict__ Kb,
    const bf16_t* __restrict__ Vb, bf16_t* __restrict__ ctxb) {
    const int S = 2048;
    __shared__ __align__(16) bf16_t Ps[2][4096];
    int tid = threadIdx.x, wave = tid >> 6, lane = tid & 63;
    int quad = lane >> 4, l16 = lane & 15;

    int f = blockIdx.x;
    int xcd = f & 7;
    int j = f >> 3;
    int hi = j >> 5;
    int idx = j & 31;
    int qtj = hi ? (15 - (idx & 15)) : (idx & 15);
    int bh = xcd * 4 + ((idx >> 4) + 2 * hi);
    int h = bh & 15, b = bh >> 4;
    int q0 = qtj * 128;

    const bf16_t* Qbh = Qb + (size_t)bh * S * 64;
    const bf16_t* Kbh = Kb + (size_t)bh * 131072;
    const bf16_t* Vbh = Vb + (size_t)bh * 131072;

    const float qs = 0.125f * 1.44269504f;
    bf16x8 aQ[2][2];
#pragma unroll
    for (int sub = 0; sub < 2; sub++) {
        const bf16_t* rq = Qbh + (size_t)(q0 + sub * 64 + wave * 16 + l16) * 64;
#pragma unroll
        for (int ks = 0; ks < 2; ks++) {
            bf16x8 t = *(const bf16x8*)(rq + ks * 32 + quad * 8);
#pragma unroll
            for (int jj = 0; jj < 8; jj++) t[jj] = (bf16_t)((float)t[jj] * qs);
            aQ[sub][ks] = t;
        }
    }

    float L[2] = {0.f, 0.f};
    f32x4 O[2][4];
#pragma unroll
    for (int sub = 0; sub < 2; sub++)
#pragma unroll
        for (int i = 0; i < 4; i++) O[sub][i] = (f32x4){0.f, 0.f, 0.f, 0.f};

    int koff[4][2];
#pragma unroll
    for (int nt = 0; nt < 4; nt++)
#pragma unroll
        for (int ks = 0; ks < 2; ks++)
            koff[nt][ks] = (nt * 16 + l16) * 64 + ((ks * 4 + quad) ^ (l16 & 7)) * 8;

    int tmax = 2 * qtj + 2;  // even
    bf16x8 kfA[4][2], vfA[4][2], kfB[4][2], vfB[4][2];
    attn_load(kfA, vfA, Kbh, Vbh, 0, koff);
#pragma unroll 1
    for (int kt = 0; kt < tmax; kt += 2) {
        attn_load(kfB, vfB, Kbh, Vbh, kt + 1, koff);   // in flight during A's compute
        attn_proc(kt, tmax, q0, kfA, vfA, aQ, L, O, Ps[0], Ps[1],
                  wave, quad, l16);
        if (kt + 2 < tmax)
            attn_load(kfA, vfA, Kbh, Vbh, kt + 2, koff);  // in flight during B's compute
        attn_proc(kt + 1, tmax, q0, kfB, vfB, aQ, L, O, Ps[0], Ps[1],
                  wave, quad, l16);
    }

#pragma unroll
    for (int sub = 0; sub < 2; sub++) {
        float il[4];
#pragma unroll
        for (int rr = 0; rr < 4; rr++) il[rr] = 1.f / __shfl(L[sub], quad * 4 + rr);
#pragma unroll
        for (int nt = 0; nt < 4; nt++) {
#pragma unroll
            for (int rr = 0; rr < 4; rr++) {
                int qoff = q0 + sub * 64 + wave * 16 + quad * 4 + rr;
                int col = h * 64 + nt * 16 + l16;
                ctxb[(size_t)(b * 2048 + qoff) * 1024 + col] =
                    (bf16_t)(O[sub][nt][rr] * il[rr]);
            }
        }
    }
}

// ---------------- out projection (r6 body, unchanged) ----------------
__global__ __launch_bounds__(256) void out_k(
    const bf16_t* __restrict__ ctxb, const bf16_t* __restrict__ WoT,
    const float* __restrict__ bo, float* __restrict__ out) {
    const int KD = 1024;
    __shared__ __align__(16) bf16_t As[2][2048];
    __shared__ __align__(16) bf16_t Bs[2][4096];
    int tid = threadIdx.x;
    int wave = tid >> 6, lane = tid & 63;
    int quad = lane >> 4, l16 = lane & 15;
    int wm = wave >> 1, wn = wave & 1;
    int m0 = blockIdx.x * 64;
    int n0 = blockIdx.y * 128;

    int r = tid >> 2;
    int c8 = (((tid & 3) ^ ((tid >> 3) & 3))) * 8;
    const bf16_t* gA  = ctxb + (size_t)(m0 + r) * KD + c8;
    const bf16_t* gB0 = WoT + (size_t)(n0 + r) * KD + c8;
    const bf16_t* gB1 = WoT + (size_t)(n0 + 64 + r) * KD + c8;

    f32x4 acc[2][4];
#pragma unroll
    for (int i = 0; i < 2; i++)
#pragma unroll
        for (int j = 0; j < 4; j++) acc[i][j] = (f32x4){0.f, 0.f, 0.f, 0.f};

    int4 sa = *(const int4*)gA;
    int4 sb0 = *(const int4*)gB0, sb1 = *(const int4*)gB1;
    *(int4*)(As[0] + tid * 8) = sa;
    *(int4*)(Bs[0] + tid * 8) = sb0;
    *(int4*)(Bs[0] + 2048 + tid * 8) = sb1;
    sa = *(const int4*)(gA + 32);
    sb0 = *(const int4*)(gB0 + 32); sb1 = *(const int4*)(gB1 + 32);

    int csw = (quad ^ ((l16 >> 1) & 3)) * 8;
#pragma unroll 1
    for (int kk = 0; kk < 32; kk += 2) {
        barrier_lgkm();
        bf16x8 af[2], bfr[4];
#pragma unroll
        for (int mt = 0; mt < 2; mt++)
            af[mt] = *(const bf16x8*)(As[0] + (wm * 32 + mt * 16 + l16) * 32 + csw);
#pragma unroll
        for (int nt = 0; nt < 4; nt++)
            bfr[nt] = *(const bf16x8*)(Bs[0] + (wn * 64 + nt * 16 + l16) * 32 + csw);
        *(int4*)(As[1] + tid * 8) = sa;
        *(int4*)(Bs[1] + tid * 8) = sb0;
        *(int4*)(Bs[1] + 2048 + tid * 8) = sb1;
        if (kk + 2 < 32) {
            int k0 = (kk + 2) * 32;
            sa = *(const int4*)(gA + k0);
            sb0 = *(const int4*)(gB0 + k0); sb1 = *(const int4*)(gB1 + k0);
        }
#pragma unroll
        for (int mt = 0; mt < 2; mt++)
#pragma unroll
            for (int nt = 0; nt < 4; nt++)
                acc[mt][nt] = __builtin_amdgcn_mfma_f32_16x16x32_bf16(
                    af[mt], bfr[nt], acc[mt][nt], 0, 0, 0);
        barrier_lgkm();
#pragma unroll
        for (int mt = 0; mt < 2; mt++)
            af[mt] = *(const bf16x8*)(As[1] + (wm * 32 + mt * 16 + l16) * 32 + csw);
#pragma unroll
        for (int nt = 0; nt < 4; nt++)
            bfr[nt] = *(const bf16x8*)(Bs[1] + (wn * 64 + nt * 16 + l16) * 32 + csw);
        if (kk + 2 < 32) {
            *(int4*)(As[0] + tid * 8) = sa;
            *(int4*)(Bs[0] + tid * 8) = sb0;
            *(int4*)(Bs[0] + 2048 + tid * 8) = sb1;
            if (kk + 3 < 32) {
                int k0 = (kk + 3) * 32;
                sa = *(const int4*)(gA + k0);
                sb0 = *(const int4*)(gB0 + k0); sb1 = *(const int4*)(gB1 + k0);
            }
        }
#pragma unroll
        for (int mt = 0; mt < 2; mt++)
#pragma unroll
            for (int nt = 0; nt < 4; nt++)
                acc[mt][nt] = __builtin_amdgcn_mfma_f32_16x16x32_bf16(
                    af[mt], bfr[nt], acc[mt][nt], 0, 0, 0);
    }

#pragma unroll
    for (int mt = 0; mt < 2; mt++) {
        int mg_base = m0 + wm * 32 + mt * 16 + quad * 4;
#pragma unroll
        for (int nt = 0; nt < 4; nt++) {
            int ng = n0 + wn * 64 + nt * 16 + l16;
            float bv = bo[ng];
#pragma unroll
            for (int rr = 0; rr < 4; rr++) {
                int mg = mg_base + rr;
                out[(size_t)mg * 1024 + ng] = acc[mt][nt][rr] + bv;
            }
        }
    }
}

extern "C" void kernel_launch(void* const* d_in, const int* in_sizes, int n_in,
                              void* d_out, int out_size, void* d_ws, size_t ws_size,
                              hipStream_t stream) {
    const float* x  = (const float*)d_in[0];
    const float* Wq = (const float*)d_in[1];
    const float* Wk = (const float*)d_in[2];
    const float* Wv = (const float*)d_in[3];
    const float* Wo = (const float*)d_in[4];
    const float* bo = (const float*)d_in[5];
    float* out = (float*)d_out;
    char* ws = (char*)d_ws;

    bf16_t* xb   = (bf16_t*)ws;                  // 8 MB
    bf16_t* WTs  = (bf16_t*)(ws + (8u << 20));   // 4x2 MB
    bf16_t* Qb   = (bf16_t*)(ws + (16u << 20));  // 8 MB natural
    bf16_t* Kb   = (bf16_t*)(ws + (24u << 20));  // 8 MB tiled-swizzled
    bf16_t* Vb   = (bf16_t*)(ws + (32u << 20));  // 8 MB tiled-swizzled V^T
    bf16_t* ctxb = (bf16_t*)(ws + (40u << 20));  // 8 MB

    prep_k<<<5120, 256, 0, stream>>>(x, Wq, Wk, Wv, Wo, xb, WTs);
    qkv_k<<<dim3(32, 8, 3), 256, 0, stream>>>(xb, WTs, Qb, Kb, Vb);
    attn_k<<<512, 256, 0, stream>>>(Qb, Kb, Vb, ctxb);
    out_k<<<dim3(64, 8), 256, 0, stream>>>(ctxb, WTs + 3145728, bo, out);
}

// Round 14
// 175.873 us; speedup vs baseline: 1.1199x; 1.0873x over previous
//
#include <hip/hip_runtime.h>
#include <hip/hip_bf16.h>

// Round 14: attn = r11's exact 100-VGPR body (best known, 44.2us) but with
// SINGLE-WAVE blocks (64 thr), 2048 blocks. r11's 4 waves/block never
// interact (no barriers, wave-private Ps) -> splitting them lifts resident
// waves/CU from 8 to ~16 (wg-slot limited), 2x the latency hiding for the
// serial S->exp->Ps->PV chain (r12/r13 triangulated attn as latency-bound:
// occupancy is the only knob that ever moved it). Heavy-first qtj order
// within each XCD fixes tail imbalance; XCD pinning keeps FETCH ~12GB.
// prep/qkv/out unchanged.

typedef __bf16 bf16_t;
typedef __bf16 bf16x4 __attribute__((ext_vector_type(4)));
typedef __bf16 bf16x8 __attribute__((ext_vector_type(8)));
typedef float f32x4 __attribute__((ext_vector_type(4)));

__device__ __forceinline__ void barrier_lgkm() {
    asm volatile("s_waitcnt lgkmcnt(0)\n\ts_barrier" ::: "memory");
}

// Ps slab is per-block (single wave): rowbase = l16*64.
__device__ __forceinline__ float exp_pwrite(f32x4 sc[4], bf16_t* Ps,
                                            int quad, int l16) {
    float part = 0.f;
    int rowbase = l16 * 64;
    int gran = (quad & 1) * 4;
    int chi = quad >> 1;
#pragma unroll
    for (int nt = 0; nt < 4; nt++) {
        f32x4 p;
#pragma unroll
        for (int rr = 0; rr < 4; rr++) {
            p[rr] = __builtin_amdgcn_exp2f(sc[nt][rr]);
            part += p[rr];
        }
        bf16x4 pb;
#pragma unroll
        for (int rr = 0; rr < 4; rr++) pb[rr] = (bf16_t)p[rr];
        int cc = (nt * 2 + chi) ^ (l16 & 7);
        *(bf16x4*)(Ps + rowbase + cc * 8 + gran) = pb;
    }
    part += __shfl_xor(part, 16);
    part += __shfl_xor(part, 32);
    return part;
}

// ---------------- prep: fused x cvt + 4x weight transpose ----------------
__global__ __launch_bounds__(256) void prep_k(
    const float* __restrict__ x, const float* __restrict__ W0,
    const float* __restrict__ W1, const float* __restrict__ W2,
    const float* __restrict__ W3, bf16_t* __restrict__ xb,
    bf16_t* __restrict__ WTs) {
    __shared__ bf16_t T[64][65];
    int t = threadIdx.x;
    int blk = blockIdx.x;
    if (blk < 4096) {
        int i = blk * 256 + t;
        float4 v = ((const float4*)x)[i];
        bf16x4 o;
        o[0] = (bf16_t)v.x; o[1] = (bf16_t)v.y;
        o[2] = (bf16_t)v.z; o[3] = (bf16_t)v.w;
        ((bf16x4*)xb)[i] = o;
        return;
    }
    int jj = blk - 4096;
    int k0 = (jj & 15) * 64, n0 = ((jj >> 4) & 15) * 64, z = jj >> 8;
    const float* W = (z == 0) ? W0 : (z == 1) ? W1 : (z == 2) ? W2 : W3;
    bf16_t* WT = WTs + (size_t)z * 1048576;
#pragma unroll
    for (int c = 0; c < 4; c++) {
        int idx = c * 256 + t;
        int row = idx >> 4, col4 = (idx & 15) * 4;
        float4 v = *(const float4*)(W + (k0 + row) * 1024 + n0 + col4);
        T[row][col4 + 0] = (bf16_t)v.x;
        T[row][col4 + 1] = (bf16_t)v.y;
        T[row][col4 + 2] = (bf16_t)v.z;
        T[row][col4 + 3] = (bf16_t)v.w;
    }
    __syncthreads();
#pragma unroll
    for (int c = 0; c < 4; c++) {
        int idx = c * 256 + t;
        int nrow = idx >> 4, kc4 = (idx & 15) * 4;
        bf16x4 o;
        o[0] = T[kc4 + 0][nrow];
        o[1] = T[kc4 + 1][nrow];
        o[2] = T[kc4 + 2][nrow];
        o[3] = T[kc4 + 3][nrow];
        *(bf16x4*)(WT + (n0 + nrow) * 1024 + k0 + kc4) = o;
    }
}

// ---------------- qkv GEMM (r6 body, unchanged) ----------------
__global__ __launch_bounds__(256) void qkv_k(
    const bf16_t* __restrict__ xb, const bf16_t* __restrict__ WTs,
    bf16_t* __restrict__ Qb, bf16_t* __restrict__ Kb, bf16_t* __restrict__ Vb) {
    const int KD = 1024;
    __shared__ __align__(16) bf16_t As[2][4096];
    __shared__ __align__(16) bf16_t Bs[2][4096];
    int tid = threadIdx.x;
    int wave = tid >> 6, lane = tid & 63;
    int quad = lane >> 4, l16 = lane & 15;
    int wm = wave >> 1, wn = wave & 1;
    int z = blockIdx.z;
    const bf16_t* BT = WTs + (size_t)z * 1048576;
    int m0 = blockIdx.x * 128;
    int n0 = blockIdx.y * 128;

    int r = tid >> 2;
    int c8 = (((tid & 3) ^ ((tid >> 3) & 3))) * 8;
    const bf16_t* gA0 = xb + (size_t)(m0 + r) * KD + c8;
    const bf16_t* gA1 = xb + (size_t)(m0 + 64 + r) * KD + c8;
    const bf16_t* gB0 = BT + (size_t)(n0 + r) * KD + c8;
    const bf16_t* gB1 = BT + (size_t)(n0 + 64 + r) * KD + c8;

    f32x4 acc[4][4];
#pragma unroll
    for (int i = 0; i < 4; i++)
#pragma unroll
        for (int j = 0; j < 4; j++) acc[i][j] = (f32x4){0.f, 0.f, 0.f, 0.f};

    int4 sa0 = *(const int4*)gA0, sa1 = *(const int4*)gA1;
    int4 sb0 = *(const int4*)gB0, sb1 = *(const int4*)gB1;
    *(int4*)(As[0] + tid * 8) = sa0;
    *(int4*)(As[0] + 2048 + tid * 8) = sa1;
    *(int4*)(Bs[0] + tid * 8) = sb0;
    *(int4*)(Bs[0] + 2048 + tid * 8) = sb1;
    sa0 = *(const int4*)(gA0 + 32); sa1 = *(const int4*)(gA1 + 32);
    sb0 = *(const int4*)(gB0 + 32); sb1 = *(const int4*)(gB1 + 32);

    int csw = (quad ^ ((l16 >> 1) & 3)) * 8;
#pragma unroll 1
    for (int kk = 0; kk < 32; kk += 2) {
        barrier_lgkm();
        bf16x8 af[4], bfr[4];
#pragma unroll
        for (int mt = 0; mt < 4; mt++)
            af[mt] = *(const bf16x8*)(As[0] + (wm * 64 + mt * 16 + l16) * 32 + csw);
#pragma unroll
        for (int nt = 0; nt < 4; nt++)
            bfr[nt] = *(const bf16x8*)(Bs[0] + (wn * 64 + nt * 16 + l16) * 32 + csw);
        *(int4*)(As[1] + tid * 8) = sa0;
        *(int4*)(As[1] + 2048 + tid * 8) = sa1;
        *(int4*)(Bs[1] + tid * 8) = sb0;
        *(int4*)(Bs[1] + 2048 + tid * 8) = sb1;
        if (kk + 2 < 32) {
            int k0 = (kk + 2) * 32;
            sa0 = *(const int4*)(gA0 + k0); sa1 = *(const int4*)(gA1 + k0);
            sb0 = *(const int4*)(gB0 + k0); sb1 = *(const int4*)(gB1 + k0);
        }
        if (z == 2) {
#pragma unroll
            for (int mt = 0; mt < 4; mt++)
#pragma unroll
                for (int nt = 0; nt < 4; nt++)
                    acc[mt][nt] = __builtin_amdgcn_mfma_f32_16x16x32_bf16(
                        bfr[nt], af[mt], acc[mt][nt], 0, 0, 0);
        } else {
#pragma unroll
            for (int mt = 0; mt < 4; mt++)
#pragma unroll
                for (int nt = 0; nt < 4; nt++)
                    acc[mt][nt] = __builtin_amdgcn_mfma_f32_16x16x32_bf16(
                        af[mt], bfr[nt], acc[mt][nt], 0, 0, 0);
        }
        barrier_lgkm();
#pragma unroll
        for (int mt = 0; mt < 4; mt++)
            af[mt] = *(const bf16x8*)(As[1] + (wm * 64 + mt * 16 + l16) * 32 + csw);
#pragma unroll
        for (int nt = 0; nt < 4; nt++)
            bfr[nt] = *(const bf16x8*)(Bs[1] + (wn * 64 + nt * 16 + l16) * 32 + csw);
        if (kk + 2 < 32) {
            *(int4*)(As[0] + tid * 8) = sa0;
            *(int4*)(As[0] + 2048 + tid * 8) = sa1;
            *(int4*)(Bs[0] + tid * 8) = sb0;
            *(int4*)(Bs[0] + 2048 + tid * 8) = sb1;
            if (kk + 3 < 32) {
                int k0 = (kk + 3) * 32;
                sa0 = *(const int4*)(gA0 + k0); sa1 = *(const int4*)(gA1 + k0);
                sb0 = *(const int4*)(gB0 + k0); sb1 = *(const int4*)(gB1 + k0);
            }
        }
        if (z == 2) {
#pragma unroll
            for (int mt = 0; mt < 4; mt++)
#pragma unroll
                for (int nt = 0; nt < 4; nt++)
                    acc[mt][nt] = __builtin_amdgcn_mfma_f32_16x16x32_bf16(
                        bfr[nt], af[mt], acc[mt][nt], 0, 0, 0);
        } else {
#pragma unroll
            for (int mt = 0; mt < 4; mt++)
#pragma unroll
                for (int nt = 0; nt < 4; nt++)
                    acc[mt][nt] = __builtin_amdgcn_mfma_f32_16x16x32_bf16(
                        af[mt], bfr[nt], acc[mt][nt], 0, 0, 0);
        }
    }

    if (z == 0) {
#pragma unroll
        for (int mt = 0; mt < 4; mt++) {
            int mg_base = m0 + wm * 64 + mt * 16 + quad * 4;
#pragma unroll
            for (int nt = 0; nt < 4; nt++) {
                int ng = n0 + wn * 64 + nt * 16 + l16;
                int h = ng >> 6, d = ng & 63;
#pragma unroll
                for (int rr = 0; rr < 4; rr++) {
                    int mg = mg_base + rr;
                    int b = mg >> 11, s = mg & 2047;
                    Qb[(((size_t)(b * 16 + h) * 2048) + s) * 64 + d] =
                        (bf16_t)acc[mt][nt][rr];
                }
            }
        }
    } else if (z == 1) {
#pragma unroll
        for (int mt = 0; mt < 4; mt++) {
            int mg_base = m0 + wm * 64 + mt * 16 + quad * 4;
#pragma unroll
            for (int nt = 0; nt < 4; nt++) {
                int ng = n0 + wn * 64 + nt * 16 + l16;
                int h = ng >> 6, dd = ng & 63;
#pragma unroll
                for (int rr = 0; rr < 4; rr++) {
                    int mg = mg_base + rr;
                    int b = mg >> 11, sl = mg & 2047;
                    int kt = sl >> 6, row = sl & 63;
                    int cc = (dd >> 3) ^ (row & 7);
                    Kb[(size_t)(b * 16 + h) * 131072 + kt * 4096 + row * 64 +
                       cc * 8 + (dd & 7)] = (bf16_t)acc[mt][nt][rr];
                }
            }
        }
    } else {
#pragma unroll
        for (int mt = 0; mt < 4; mt++) {
            int sg = m0 + wm * 64 + mt * 16 + l16;
            int b = sg >> 11, sl = sg & 2047;
            int kt = sl >> 6, srow = sl & 63;
#pragma unroll
            for (int nt = 0; nt < 4; nt++) {
                int dg_base = n0 + wn * 64 + nt * 16 + quad * 4;
#pragma unroll
                for (int rr = 0; rr < 4; rr++) {
                    int dg = dg_base + rr;
                    int h = dg >> 6, dd = dg & 63;
                    int cc = (srow >> 3) ^ (dd & 7);
                    Vb[(size_t)(b * 16 + h) * 131072 + kt * 4096 + dd * 64 +
                       cc * 8 + (srow & 7)] = (bf16_t)acc[mt][nt][rr];
                }
            }
        }
    }
}

// ---------------- attention: single-wave blocks, no-LDS K/V ----------------
// grid 2048 x 64thr. f&7 = XCD; r=f>>3 (0..255): qtj = 15-(r>>4) heavy-first,
// rl = r&15: bh = xcd*4 + (rl>>2), wgrp = rl&3 (16-row slice of 128-row tile).
__global__ __launch_bounds__(64) void attn_k(
    const bf16_t* __restrict__ Qb, const bf16_t* __restrict__ Kb,
    const bf16_t* __restrict__ Vb, bf16_t* __restrict__ ctxb) {
    const int S = 2048;
    __shared__ __align__(16) bf16_t Ps[2][1024];
    int lane = threadIdx.x & 63;
    int quad = lane >> 4, l16 = lane & 15;

    int f = blockIdx.x;
    int xcd = f & 7;
    int r = f >> 3;
    int qtj = 15 - (r >> 4);
    int rl = r & 15;
    int bh = xcd * 4 + (rl >> 2);
    int wgrp = rl & 3;
    int h = bh & 15, b = bh >> 4;
    int q0 = qtj * 128;

    const bf16_t* Qbh = Qb + (size_t)bh * S * 64;
    const bf16_t* Kbh = Kb + (size_t)bh * 131072;
    const bf16_t* Vbh = Vb + (size_t)bh * 131072;

    const float qs = 0.125f * 1.44269504f;
    bf16x8 aQ[2][2];
#pragma unroll
    for (int sub = 0; sub < 2; sub++) {
        const bf16_t* rq = Qbh + (size_t)(q0 + sub * 64 + wgrp * 16 + l16) * 64;
#pragma unroll
        for (int ks = 0; ks < 2; ks++) {
            bf16x8 t = *(const bf16x8*)(rq + ks * 32 + quad * 8);
#pragma unroll
            for (int jj = 0; jj < 8; jj++) t[jj] = (bf16_t)((float)t[jj] * qs);
            aQ[sub][ks] = t;
        }
    }

    float L[2] = {0.f, 0.f};
    f32x4 O[2][4];
#pragma unroll
    for (int sub = 0; sub < 2; sub++)
#pragma unroll
        for (int i = 0; i < 4; i++) O[sub][i] = (f32x4){0.f, 0.f, 0.f, 0.f};

    int koff[4][2];
#pragma unroll
    for (int nt = 0; nt < 4; nt++)
#pragma unroll
        for (int ks = 0; ks < 2; ks++)
            koff[nt][ks] = (nt * 16 + l16) * 64 + ((ks * 4 + quad) ^ (l16 & 7)) * 8;

    int tmax = 2 * qtj + 2;
#pragma unroll 1
    for (int kt = 0; kt < tmax; kt++) {
        const bf16_t* kbase = Kbh + kt * 4096;
        const bf16_t* vbase = Vbh + kt * 4096;
        bf16x8 kf[4][2], vf[4][2];
#pragma unroll
        for (int nt = 0; nt < 4; nt++)
#pragma unroll
            for (int ks = 0; ks < 2; ks++) {
                kf[nt][ks] = *(const bf16x8*)(kbase + koff[nt][ks]);
                vf[nt][ks] = *(const bf16x8*)(vbase + koff[nt][ks]);
            }

        bool do_lo = (kt < tmax - 1);
        if (do_lo) {
            f32x4 sc[4];
#pragma unroll
            for (int nt = 0; nt < 4; nt++) {
                f32x4 ss = (f32x4){0.f, 0.f, 0.f, 0.f};
                ss = __builtin_amdgcn_mfma_f32_16x16x32_bf16(kf[nt][0], aQ[0][0], ss, 0, 0, 0);
                ss = __builtin_amdgcn_mfma_f32_16x16x32_bf16(kf[nt][1], aQ[0][1], ss, 0, 0, 0);
                sc[nt] = ss;
            }
            if (kt == tmax - 2) {
                int qg = q0 + wgrp * 16 + l16;
#pragma unroll
                for (int nt = 0; nt < 4; nt++)
#pragma unroll
                    for (int rr = 0; rr < 4; rr++)
                        if (kt * 64 + nt * 16 + quad * 4 + rr > qg) sc[nt][rr] = -1e30f;
            }
            L[0] += exp_pwrite(sc, Ps[0], quad, l16);
        }
        {
            f32x4 sc[4];
#pragma unroll
            for (int nt = 0; nt < 4; nt++) {
                f32x4 ss = (f32x4){0.f, 0.f, 0.f, 0.f};
                ss = __builtin_amdgcn_mfma_f32_16x16x32_bf16(kf[nt][0], aQ[1][0], ss, 0, 0, 0);
                ss = __builtin_amdgcn_mfma_f32_16x16x32_bf16(kf[nt][1], aQ[1][1], ss, 0, 0, 0);
                sc[nt] = ss;
            }
            if (kt == tmax - 1) {
                int qg = q0 + 64 + wgrp * 16 + l16;
#pragma unroll
                for (int nt = 0; nt < 4; nt++)
#pragma unroll
                    for (int rr = 0; rr < 4; rr++)
                        if (kt * 64 + nt * 16 + quad * 4 + rr > qg) sc[nt][rr] = -1e30f;
            }
            L[1] += exp_pwrite(sc, Ps[1], quad, l16);
        }

        // O += P @ V (Ps is block-private = wave-private; in-order within wave)
#pragma unroll
        for (int ks = 0; ks < 2; ks++) {
            int csw = ((ks * 4 + quad) ^ (l16 & 7)) * 8;
            bf16x8 aPhi = *(const bf16x8*)(Ps[1] + l16 * 64 + csw);
            bf16x8 aPlo;
            if (do_lo) aPlo = *(const bf16x8*)(Ps[0] + l16 * 64 + csw);
#pragma unroll
            for (int nt = 0; nt < 4; nt++) {
                O[1][nt] = __builtin_amdgcn_mfma_f32_16x16x32_bf16(aPhi, vf[nt][ks],
                                                                   O[1][nt], 0, 0, 0);
                if (do_lo)
                    O[0][nt] = __builtin_amdgcn_mfma_f32_16x16x32_bf16(aPlo, vf[nt][ks],
                                                                       O[0][nt], 0, 0, 0);
            }
        }
    }

#pragma unroll
    for (int sub = 0; sub < 2; sub++) {
        float il[4];
#pragma unroll
        for (int rr = 0; rr < 4; rr++) il[rr] = 1.f / __shfl(L[sub], quad * 4 + rr);
#pragma unroll
        for (int nt = 0; nt < 4; nt++) {
#pragma unroll
            for (int rr = 0; rr < 4; rr++) {
                int qoff = q0 + sub * 64 + wgrp * 16 + quad * 4 + rr;
                int col = h * 64 + nt * 16 + l16;
                ctxb[(size_t)(b * 2048 + qoff) * 1024 + col] =
                    (bf16_t)(O[sub][nt][rr] * il[rr]);
            }
        }
    }
}

// ---------------- out projection (r6 body, unchanged) ----------------
__global__ __launch_bounds__(256) void out_k(
    const bf16_t* __restrict__ ctxb, const bf16_t* __restrict__ WoT,
    const float* __restrict__ bo, float* __restrict__ out) {
    const int KD = 1024;
    __shared__ __align__(16) bf16_t As[2][2048];
    __shared__ __align__(16) bf16_t Bs[2][4096];
    int tid = threadIdx.x;
    int wave = tid >> 6, lane = tid & 63;
    int quad = lane >> 4, l16 = lane & 15;
    int wm = wave >> 1, wn = wave & 1;
    int m0 = blockIdx.x * 64;
    int n0 = blockIdx.y * 128;

    int r = tid >> 2;
    int c8 = (((tid & 3) ^ ((tid >> 3) & 3))) * 8;
    const bf16_t* gA  = ctxb + (size_t)(m0 + r) * KD + c8;
    const bf16_t* gB0 = WoT + (size_t)(n0 + r) * KD + c8;
    const bf16_t* gB1 = WoT + (size_t)(n0 + 64 + r) * KD + c8;

    f32x4 acc[2][4];
#pragma unroll
    for (int i = 0; i < 2; i++)
#pragma unroll
        for (int j = 0; j < 4; j++) acc[i][j] = (f32x4){0.f, 0.f, 0.f, 0.f};

    int4 sa = *(const int4*)gA;
    int4 sb0 = *(const int4*)gB0, sb1 = *(const int4*)gB1;
    *(int4*)(As[0] + tid * 8) = sa;
    *(int4*)(Bs[0] + tid * 8) = sb0;
    *(int4*)(Bs[0] + 2048 + tid * 8) = sb1;
    sa = *(const int4*)(gA + 32);
    sb0 = *(const int4*)(gB0 + 32); sb1 = *(const int4*)(gB1 + 32);

    int csw = (quad ^ ((l16 >> 1) & 3)) * 8;
#pragma unroll 1
    for (int kk = 0; kk < 32; kk += 2) {
        barrier_lgkm();
        bf16x8 af[2], bfr[4];
#pragma unroll
        for (int mt = 0; mt < 2; mt++)
            af[mt] = *(const bf16x8*)(As[0] + (wm * 32 + mt * 16 + l16) * 32 + csw);
#pragma unroll
        for (int nt = 0; nt < 4; nt++)
            bfr[nt] = *(const bf16x8*)(Bs[0] + (wn * 64 + nt * 16 + l16) * 32 + csw);
        *(int4*)(As[1] + tid * 8) = sa;
        *(int4*)(Bs[1] + tid * 8) = sb0;
        *(int4*)(Bs[1] + 2048 + tid * 8) = sb1;
        if (kk + 2 < 32) {
            int k0 = (kk + 2) * 32;
            sa = *(const int4*)(gA + k0);
            sb0 = *(const int4*)(gB0 + k0); sb1 = *(const int4*)(gB1 + k0);
        }
#pragma unroll
        for (int mt = 0; mt < 2; mt++)
#pragma unroll
            for (int nt = 0; nt < 4; nt++)
                acc[mt][nt] = __builtin_amdgcn_mfma_f32_16x16x32_bf16(
                    af[mt], bfr[nt], acc[mt][nt], 0, 0, 0);
        barrier_lgkm();
#pragma unroll
        for (int mt = 0; mt < 2; mt++)
            af[mt] = *(const bf16x8*)(As[1] + (wm * 32 + mt * 16 + l16) * 32 + csw);
#pragma unroll
        for (int nt = 0; nt < 4; nt++)
            bfr[nt] = *(const bf16x8*)(Bs[1] + (wn * 64 + nt * 16 + l16) * 32 + csw);
        if (kk + 2 < 32) {
            *(int4*)(As[0] + tid * 8) = sa;
            *(int4*)(Bs[0] + tid * 8) = sb0;
            *(int4*)(Bs[0] + 2048 + tid * 8) = sb1;
            if (kk + 3 < 32) {
                int k0 = (kk + 3) * 32;
                sa = *(const int4*)(gA + k0);
                sb0 = *(const int4*)(gB0 + k0); sb1 = *(const int4*)(gB1 + k0);
            }
        }
#pragma unroll
        for (int mt = 0; mt < 2; mt++)
#pragma unroll
            for (int nt = 0; nt < 4; nt++)
                acc[mt][nt] = __builtin_amdgcn_mfma_f32_16x16x32_bf16(
                    af[mt], bfr[nt], acc[mt][nt], 0, 0, 0);
    }

#pragma unroll
    for (int mt = 0; mt < 2; mt++) {
        int mg_base = m0 + wm * 32 + mt * 16 + quad * 4;
#pragma unroll
        for (int nt = 0; nt < 4; nt++) {
            int ng = n0 + wn * 64 + nt * 16 + l16;
            float bv = bo[ng];
#pragma unroll
            for (int rr = 0; rr < 4; rr++) {
                int mg = mg_base + rr;
                out[(size_t)mg * 1024 + ng] = acc[mt][nt][rr] + bv;
            }
        }
    }
}

extern "C" void kernel_launch(void* const* d_in, const int* in_sizes, int n_in,
                              void* d_out, int out_size, void* d_ws, size_t ws_size,
                              hipStream_t stream) {
    const float* x  = (const float*)d_in[0];
    const float* Wq = (const float*)d_in[1];
    const float* Wk = (const float*)d_in[2];
    const float* Wv = (const float*)d_in[3];
    const float* Wo = (const float*)d_in[4];
    const float* bo = (const float*)d_in[5];
    float* out = (float*)d_out;
    char* ws = (char*)d_ws;

    bf16_t* xb   = (bf16_t*)ws;                  // 8 MB
    bf16_t* WTs  = (bf16_t*)(ws + (8u << 20));   // 4x2 MB
    bf16_t* Qb   = (bf16_t*)(ws + (16u << 20));  // 8 MB natural
    bf16_t* Kb   = (bf16_t*)(ws + (24u << 20));  // 8 MB tiled-swizzled
    bf16_t* Vb   = (bf16_t*)(ws + (32u << 20));  // 8 MB tiled-swizzled V^T
    bf16_t* ctxb = (bf16_t*)(ws + (40u << 20));  // 8 MB

    prep_k<<<5120, 256, 0, stream>>>(x, Wq, Wk, Wv, Wo, xb, WTs);
    qkv_k<<<dim3(32, 8, 3), 256, 0, stream>>>(xb, WTs, Qb, Kb, Vb);
    attn_k<<<2048, 64, 0, stream>>>(Qb, Kb, Vb, ctxb);
    out_k<<<dim3(64, 8), 256, 0, stream>>>(ctxb, WTs + 3145728, bo, out);
}